// Round 2
// baseline (32.289 us; speedup 1.0000x reference)
//
#include <hip/hip_runtime.h>
#include <hip/hip_cooperative_groups.h>

namespace cg = cooperative_groups;

// CenterLoss collapses algebraically: after masking, only distmat[b, label_b]
// survives per row; every other entry is 0 -> clamps to 1e-12.
// loss = (1/B) * sum_b clip(||x_b - c_{label_b}||^2, 1e-12, 1e12) + (C-1)*1e-12
//
// Single cooperative dispatch: partials -> grid.sync -> final reduce.
// Two-dispatch version measured 11.7 us with ~0.2 us of actual memory time,
// i.e. pure launch overhead; this removes one graph node + the dependency.

#define BATCH 1024
#define FEAT_DIM 128
#define NUM_CLASSES 100000
#define NBLK 64
#define NTHR 256

__global__ void center_loss_coop(const float* __restrict__ x,
                                 const int* __restrict__ label,
                                 const float* __restrict__ centers,
                                 float* __restrict__ out,
                                 float* __restrict__ partials) {
    cg::grid_group grid = cg::this_grid();

    const int lane  = threadIdx.x & 63;
    const int wid   = threadIdx.x >> 6;          // wave id in block: 0..3
    const int gwave = blockIdx.x * 4 + wid;      // global wave: 0..255

    float wsum = 0.f;  // uniform across the wave (xor-butterfly gives all lanes the sum)
    #pragma unroll
    for (int r = 0; r < 4; ++r) {
        const int row = gwave + 256 * r;         // 4 rows per wave, stride 256
        const int lbl = label[row];              // wave-uniform scalar load
        const float2 xv = *reinterpret_cast<const float2*>(x + (size_t)row * FEAT_DIM + lane * 2);
        const float2 cv = *reinterpret_cast<const float2*>(centers + (size_t)lbl * FEAT_DIM + lane * 2);
        const float d0 = xv.x - cv.x;
        const float d1 = xv.y - cv.y;
        float s = d0 * d0 + d1 * d1;
        #pragma unroll
        for (int off = 32; off > 0; off >>= 1)
            s += __shfl_xor(s, off, 64);
        // clamp per surviving entry (faithful to reference clamp-after-mask)
        wsum += fminf(fmaxf(s, 1e-12f), 1e12f);
    }

    __shared__ float sm[4];
    if (lane == 0) sm[wid] = wsum;
    __syncthreads();
    if (threadIdx.x == 0)
        partials[blockIdx.x] = sm[0] + sm[1] + sm[2] + sm[3];

    grid.sync();  // device-scope barrier + fences (cross-XCD visibility)

    if (blockIdx.x == 0 && threadIdx.x < 64) {
        float v = partials[threadIdx.x];
        #pragma unroll
        for (int off = 32; off > 0; off >>= 1)
            v += __shfl_xor(v, off, 64);
        if (threadIdx.x == 0) {
            // B*(C-1) masked-off zeros clamp to 1e-12; /B -> (C-1)*1e-12
            out[0] = v / (float)BATCH + (float)(NUM_CLASSES - 1) * 1e-12f;
        }
    }
}

extern "C" void kernel_launch(void* const* d_in, const int* in_sizes, int n_in,
                              void* d_out, int out_size, void* d_ws, size_t ws_size,
                              hipStream_t stream) {
    const float* x       = (const float*)d_in[0];
    const int*   label   = (const int*)d_in[1];
    const float* centers = (const float*)d_in[2];
    float*       out     = (float*)d_out;
    float*       ws      = (float*)d_ws;  // needs NBLK floats = 256 B

    void* args[] = {(void*)&x, (void*)&label, (void*)&centers, (void*)&out, (void*)&ws};
    hipLaunchCooperativeKernel((void*)center_loss_coop, dim3(NBLK), dim3(NTHR),
                               args, 0, stream);
}

// Round 3
// 13.930 us; speedup vs baseline: 2.3178x; 2.3178x over previous
//
#include <hip/hip_runtime.h>

// CenterLoss collapses algebraically: after masking, only distmat[b, label_b]
// survives per row; every other entry is 0 -> clamps to 1e-12.
// loss = (1/B) * sum_b clip(||x_b - c_{label_b}||^2, 1e-12, 1e12) + (C-1)*1e-12
//
// Round-1 (two kernel nodes): 11.7 us, ~0.2 us of real memory work -> node
// overhead dominates. Round-2 (cooperative): 32 us -> coop launch in graphs is
// expensive. This round: ONE regular kernel node + a 4-byte memset node.
// Last-arriving block (device-scope atomic ticket) does the final reduce in a
// fixed butterfly order -> deterministic.

#define BATCH 1024
#define FEAT_DIM 128
#define NUM_CLASSES 100000
#define NBLK 64

__global__ __launch_bounds__(256) void center_loss_main(
        const float* __restrict__ x,
        const int* __restrict__ label,
        const float* __restrict__ centers,
        float* __restrict__ out,
        unsigned int* __restrict__ counter,
        float* __restrict__ partials) {
    const int lane = threadIdx.x & 63;
    const int wid  = threadIdx.x >> 6;           // 4 waves per block

    // Each block owns 16 rows; each wave 4 rows (one 512B row per iteration).
    const int base = blockIdx.x * 16 + wid * 4;
    float wsum = 0.f;
    #pragma unroll
    for (int r = 0; r < 4; ++r) {
        const int row = base + r;
        const int lbl = label[row];  // wave-uniform -> scalar load
        const float2 xv = *reinterpret_cast<const float2*>(x + (size_t)row * FEAT_DIM + lane * 2);
        const float2 cv = *reinterpret_cast<const float2*>(centers + (size_t)lbl * FEAT_DIM + lane * 2);
        const float d0 = xv.x - cv.x;
        const float d1 = xv.y - cv.y;
        float s = d0 * d0 + d1 * d1;
        #pragma unroll
        for (int off = 32; off > 0; off >>= 1)
            s += __shfl_xor(s, off, 64);
        // clamp per surviving entry (faithful to reference clamp-after-mask)
        wsum += fminf(fmaxf(s, 1e-12f), 1e12f);
    }

    __shared__ float sm[4];
    __shared__ int is_last;
    if (lane == 0) sm[wid] = wsum;
    __syncthreads();
    if (threadIdx.x == 0) {
        const float bsum = (sm[0] + sm[1]) + (sm[2] + sm[3]);
        // release-store partial, then take a ticket (device scope crosses XCD L2s)
        __hip_atomic_store(&partials[blockIdx.x], bsum,
                           __ATOMIC_RELEASE, __HIP_MEMORY_SCOPE_AGENT);
        const unsigned old = __hip_atomic_fetch_add(counter, 1u,
                           __ATOMIC_ACQ_REL, __HIP_MEMORY_SCOPE_AGENT);
        is_last = (old == NBLK - 1) ? 1 : 0;
    }
    __syncthreads();

    if (is_last && wid == 0) {
        float v = __hip_atomic_load(&partials[lane],
                                    __ATOMIC_ACQUIRE, __HIP_MEMORY_SCOPE_AGENT);
        #pragma unroll
        for (int off = 32; off > 0; off >>= 1)
            v += __shfl_xor(v, off, 64);
        if (lane == 0) {
            // B*(C-1) masked-off zeros clamp to 1e-12; /B -> (C-1)*1e-12
            out[0] = v * (1.0f / (float)BATCH) + (float)(NUM_CLASSES - 1) * 1e-12f;
            // self-reset for the next replay (memset node also covers this)
            __hip_atomic_store(counter, 0u,
                               __ATOMIC_RELAXED, __HIP_MEMORY_SCOPE_AGENT);
        }
    }
}

extern "C" void kernel_launch(void* const* d_in, const int* in_sizes, int n_in,
                              void* d_out, int out_size, void* d_ws, size_t ws_size,
                              hipStream_t stream) {
    const float* x       = (const float*)d_in[0];
    const int*   label   = (const int*)d_in[1];
    const float* centers = (const float*)d_in[2];
    float*       out     = (float*)d_out;

    unsigned int* counter  = (unsigned int*)d_ws;
    float*        partials = (float*)((char*)d_ws + 256);  // 64 floats

    // Counter must be 0 at kernel start on EVERY call (ws is poisoned 0xAA
    // once before timing; first correctness call sees arbitrary ws).
    hipMemsetAsync(d_ws, 0, 4, stream);
    center_loss_main<<<NBLK, 256, 0, stream>>>(x, label, centers, out, counter, partials);
}

// Round 4
// 11.272 us; speedup vs baseline: 2.8645x; 1.2358x over previous
//
#include <hip/hip_runtime.h>

// CenterLoss collapses algebraically: after masking, only distmat[b, label_b]
// survives per row; every other entry is 0 -> clamps to 1e-12.
// loss = (1/B) * sum_b clip(||x_b - c_{label_b}||^2, 1e-12, 1e12) + (C-1)*1e-12
//
// Measured node-cost ladder: 2 kernel nodes (11.7us, R1) < memset+kernel
// (13.9us, R3) < cooperative (32us, R2). Real memory work is ~0.2us -> we are
// launch-overhead-bound. This round keeps the winning 2-node structure and
// trims critical-path exec: K1 emits 64 block partials (not 1024 row values),
// K2 is a single wave with a pure shfl butterfly (no LDS, no syncthreads).

#define BATCH 1024
#define FEAT_DIM 128
#define NUM_CLASSES 100000
#define NBLK 64

__global__ __launch_bounds__(256) void center_partials(
        const float* __restrict__ x,
        const int* __restrict__ label,
        const float* __restrict__ centers,
        float* __restrict__ partials) {
    const int lane = threadIdx.x & 63;
    const int wid  = threadIdx.x >> 6;            // 4 waves per block
    const int base = blockIdx.x * 16 + wid * 4;   // 4 rows per wave

    // Hoist the 4 wave-uniform label loads so all center gathers issue
    // under a single latency exposure.
    int lbl[4];
    #pragma unroll
    for (int r = 0; r < 4; ++r) lbl[r] = label[base + r];

    float wsum = 0.f;
    #pragma unroll
    for (int r = 0; r < 4; ++r) {
        const int row = base + r;
        const float2 xv = *reinterpret_cast<const float2*>(x + (size_t)row * FEAT_DIM + lane * 2);
        const float2 cv = *reinterpret_cast<const float2*>(centers + (size_t)lbl[r] * FEAT_DIM + lane * 2);
        const float d0 = xv.x - cv.x;
        const float d1 = xv.y - cv.y;
        float s = d0 * d0 + d1 * d1;
        #pragma unroll
        for (int off = 32; off > 0; off >>= 1)
            s += __shfl_xor(s, off, 64);
        // clamp per surviving entry (faithful to reference clamp-after-mask)
        wsum += fminf(fmaxf(s, 1e-12f), 1e12f);
    }

    __shared__ float sm[4];
    if (lane == 0) sm[wid] = wsum;
    __syncthreads();
    if (threadIdx.x == 0)
        partials[blockIdx.x] = (sm[0] + sm[1]) + (sm[2] + sm[3]);
}

// One wave reduces the 64 block partials. No LDS, no __syncthreads.
__global__ __launch_bounds__(64) void center_finish(
        const float* __restrict__ partials,
        float* __restrict__ out) {
    float v = partials[threadIdx.x & 63];
    #pragma unroll
    for (int off = 32; off > 0; off >>= 1)
        v += __shfl_xor(v, off, 64);
    if (threadIdx.x == 0) {
        // B*(C-1) masked-off zeros clamp to 1e-12; /B -> (C-1)*1e-12
        out[0] = v * (1.0f / (float)BATCH) + (float)(NUM_CLASSES - 1) * 1e-12f;
    }
}

extern "C" void kernel_launch(void* const* d_in, const int* in_sizes, int n_in,
                              void* d_out, int out_size, void* d_ws, size_t ws_size,
                              hipStream_t stream) {
    const float* x       = (const float*)d_in[0];
    const int*   label   = (const int*)d_in[1];
    const float* centers = (const float*)d_in[2];
    float*       out     = (float*)d_out;
    float*       ws      = (float*)d_ws;  // 64 floats = 256 B

    center_partials<<<NBLK, 256, 0, stream>>>(x, label, centers, ws);
    center_finish<<<1, 64, 0, stream>>>(ws, out);
}